// Round 10
// baseline (19941.913 us; speedup 1.0000x reference)
//
#include <hip/hip_runtime.h>

#define SEQ  8192
#define NT   2048
#define NBLK 64
#define NTHR 512
#define LOG2E 1.4426950408889634f
#define LN2   0.6931471805599453f

#define STORE_AG(p, v) __hip_atomic_store((p), (v), __ATOMIC_RELAXED, __HIP_MEMORY_SCOPE_AGENT)

typedef unsigned int u32x4 __attribute__((ext_vector_type(4)));
typedef float f32x4 __attribute__((ext_vector_type(4)));

// Device-coherent 16B load (bypasses L1/L2 -> served from LLC). Each dword
// inside is individually tagged, so 16B-level tearing is harmless.
__device__ __forceinline__ u32x4 poll_load16(const unsigned int* p) {
    u32x4 r;
    asm volatile("global_load_dwordx4 %0, %1, off sc0 sc1\n\t"
                 "s_waitcnt vmcnt(0)"
                 : "=v"(r) : "v"(p) : "memory");
    return r;
}

// Packed state: word i of buffer t&1 = (tag<<16) | bf16(z[i]). One relaxed
// dword store publishes tag+data atomically; no flags, no fences.
__device__ __align__(16) unsigned int g_z[2][NT];
__device__ float g_gold;

__device__ __forceinline__ unsigned int f32_to_bf16(float f) {
    unsigned int u = __float_as_uint(f);
    return (u + 0x7FFFu + ((u >> 16) & 1u)) >> 16;  // RNE
}

// ---- init: z0 = exp(tstart + feats[0]) tagged 0; other buffer invalidated ----
__global__ void crf_init(const float* __restrict__ feats,
                         const float* __restrict__ tstart) {
    int i = blockIdx.x * blockDim.x + threadIdx.x;
    if (i < NT) {
        float z0 = __builtin_exp2f((tstart[i] + feats[i]) * LOG2E);
        g_z[0][i] = f32_to_bf16(z0);   // tag 0
        g_z[1][i] = 0xFFFF0000u;       // tag never matched (t <= 8191)
    }
}

// ---- gold path score (verified rounds 1-9) ----
__global__ void crf_gold(const float* __restrict__ feats,
                         const float* __restrict__ trans,
                         const float* __restrict__ tstart,
                         const float* __restrict__ tstop,
                         const int*   __restrict__ tags) {
    __shared__ float part[16];
    int tid = threadIdx.x;
    float acc = 0.f;
    for (int t = 1 + tid; t < SEQ; t += 1024) {
        int cur = tags[t], prev = tags[t - 1];
        acc += trans[(size_t)cur * NT + prev] + feats[(size_t)t * NT + cur];
    }
    #pragma unroll
    for (int m = 1; m < 64; m <<= 1) acc += __shfl_xor(acc, m, 64);
    if ((tid & 63) == 0) part[tid >> 6] = acc;
    __syncthreads();
    if (tid == 0) {
        float S = 0.f;
        #pragma unroll
        for (int w = 0; w < 16; ++w) S += part[w];
        int t0 = tags[0], tl = tags[SEQ - 1];
        g_gold = S + tstart[t0] + feats[t0] + tstop[tl];
    }
}

// ---- main recurrence: 64 blocks x 512 threads, 4 rows per wave ----
// vs R9 (single change class): halve the exchange population again. Wave wid
// owns rows j0..j0+3, j0 = 32b + 4*wid. The ds_read_b128 of w feeds all FOUR
// rows' FMAs (only E differs, in registers) -> DS-pipe unchanged. Pollers
// 32K, publishers 64 (one contiguous 128B line each), skew over 64 blocks.
// Safety proof unchanged: all polls precede barrier A, all stores follow
// barrier B => published tag t implies t-1 fully consumed => t-2 slots dead.
__global__ void __launch_bounds__(NTHR)
crf_main(const float* __restrict__ feats, const float* __restrict__ trans,
         const float* __restrict__ tstop, float* __restrict__ out) {
    const int b   = blockIdx.x;
    const int tid = threadIdx.x;
    const int wid = tid >> 6;
    const int l   = tid & 63;
    const int j0  = b * 32 + wid * 4;   // wave's first row; owns j0..j0+3

    __shared__ __align__(16) float w_lds[2][NT];   // parity double-buffer
    __shared__ float s_scale[2];
    __shared__ unsigned int pk[32];    // packed per-row results
    __shared__ float red[8];

    // E[r][u][q] = exp(T[j0+r][4l + 256u + q]) in [1, e); 128 VGPRs.
    float E0[8][4], E1[8][4], E2[8][4], E3[8][4];
    {
        const float* tr = trans + (size_t)j0 * NT + 4 * l;
        #pragma unroll
        for (int u = 0; u < 8; ++u) {
            #pragma unroll
            for (int q = 0; q < 4; ++q) {
                E0[u][q] = __builtin_exp2f(tr[(size_t)0 * NT + 256 * u + q] * LOG2E);
                E1[u][q] = __builtin_exp2f(tr[(size_t)1 * NT + 256 * u + q] * LOG2E);
                E2[u][q] = __builtin_exp2f(tr[(size_t)2 * NT + 256 * u + q] * LOG2E);
                E3[u][q] = __builtin_exp2f(tr[(size_t)3 * NT + 256 * u + q] * LOG2E);
            }
        }
    }

    // lanes 0..3: exp(feat_t[j0+l]) for step 1, kept one step ahead
    float fexp = (l < 4)
        ? __builtin_exp2f(feats[(size_t)NT + j0 + l] * LOG2E) : 0.f;
    int esum = 0;   // only block 0 / tid 0's copy is consumed

    for (int t = 1; t < SEQ; ++t) {
        const int par = (t - 1) & 1;
        const unsigned int need = (unsigned int)(t - 1);
        const unsigned int* buf = g_z[par] + 4 * tid;

        // ---- one-shot poll: 4 tagged words per thread, 1 instr per retry ----
        u32x4 v;
        do { v = poll_load16(buf); }
        while ((v.x >> 16) != need || (v.y >> 16) != need ||
               (v.z >> 16) != need || (v.w >> 16) != need);

        // unpack bf16 -> f32 into LDS as ONE 16B store
        {
            f32x4 wq;
            wq.x = __uint_as_float(v.x << 16);
            wq.y = __uint_as_float(v.y << 16);
            wq.z = __uint_as_float(v.z << 16);
            wq.w = __uint_as_float(v.w << 16);
            *(f32x4*)&w_lds[par][4 * tid] = wq;
        }

        if (tid == 0) {
            int e = (int)((v.x >> 7) & 0xFFu) - 127;   // bf16 exponent of word 0
            s_scale[par] = __uint_as_float((unsigned int)(127 - e) << 23);
            esum += e;
        }
        // prefetch next feat + exp (off critical path; lanes 0..3 only)
        float fexpnext = (l < 4 && t + 1 < SEQ)
            ? __builtin_exp2f(feats[(size_t)(t + 1) * NT + j0 + l] * LOG2E) : 0.f;
        __syncthreads();   // A: w_lds + s_scale ready

        // ---- four dots sharing each ds_read_b128 of w ----
        float a0 = 0.f, a1 = 0.f, a2 = 0.f, a3 = 0.f;
        #pragma unroll
        for (int u = 0; u < 8; ++u) {
            f32x4 wq = *(const f32x4*)&w_lds[par][4 * l + 256 * u];
            a0 = fmaf(E0[u][0], wq.x, a0);
            a1 = fmaf(E1[u][0], wq.x, a1);
            a2 = fmaf(E2[u][0], wq.x, a2);
            a3 = fmaf(E3[u][0], wq.x, a3);
            a0 = fmaf(E0[u][1], wq.y, a0);
            a1 = fmaf(E1[u][1], wq.y, a1);
            a2 = fmaf(E2[u][1], wq.y, a2);
            a3 = fmaf(E3[u][1], wq.y, a3);
            a0 = fmaf(E0[u][2], wq.z, a0);
            a1 = fmaf(E1[u][2], wq.z, a1);
            a2 = fmaf(E2[u][2], wq.z, a2);
            a3 = fmaf(E3[u][2], wq.z, a3);
            a0 = fmaf(E0[u][3], wq.w, a0);
            a1 = fmaf(E1[u][3], wq.w, a1);
            a2 = fmaf(E2[u][3], wq.w, a2);
            a3 = fmaf(E3[u][3], wq.w, a3);
        }
        #pragma unroll
        for (int m = 1; m < 64; m <<= 1) {
            a0 += __shfl_xor(a0, m, 64);
            a1 += __shfl_xor(a1, m, 64);
            a2 += __shfl_xor(a2, m, 64);
            a3 += __shfl_xor(a3, m, 64);
        }

        if (l < 4) {   // lane r finalizes row j0+r (compile-time-safe select)
            float tot = (l == 0) ? a0 : (l == 1) ? a1 : (l == 2) ? a2 : a3;
            float znew = tot * s_scale[par] * fexp;
            pk[wid * 4 + l] = ((unsigned int)t << 16) | f32_to_bf16(znew);
        }
        fexp = fexpnext;
        __syncthreads();   // B: all 32 results gathered

        // ---- ONE coalesced publication: lanes 0-31, 32 contiguous dwords ----
        if (tid < 32) STORE_AG(&g_z[t & 1][b * 32 + tid], pk[tid]);
    }

    // ---- final: lse of z_{SEQ-1} with stop transitions, minus gold ----
    if (b == 0) {
        const unsigned int need = SEQ - 1;
        const unsigned int* buf = g_z[(SEQ - 1) & 1] + 4 * tid;
        u32x4 v;
        do { v = poll_load16(buf); }
        while ((v.x >> 16) != need || (v.y >> 16) != need ||
               (v.z >> 16) != need || (v.w >> 16) != need);

        float acc =
            __uint_as_float(v.x << 16) * __builtin_exp2f(tstop[4 * tid + 0] * LOG2E) +
            __uint_as_float(v.y << 16) * __builtin_exp2f(tstop[4 * tid + 1] * LOG2E) +
            __uint_as_float(v.z << 16) * __builtin_exp2f(tstop[4 * tid + 2] * LOG2E) +
            __uint_as_float(v.w << 16) * __builtin_exp2f(tstop[4 * tid + 3] * LOG2E);
        #pragma unroll
        for (int m = 1; m < 64; m <<= 1) acc += __shfl_xor(acc, m, 64);
        if (l == 0) red[wid] = acc;
        __syncthreads();
        if (tid == 0) {
            float S = 0.f;
            #pragma unroll
            for (int w = 0; w < 8; ++w) S += red[w];
            float fwd = (__builtin_log2f(S) + (float)esum) * LN2;
            out[0] = fwd - g_gold;
        }
    }
}

extern "C" void kernel_launch(void* const* d_in, const int* in_sizes, int n_in,
                              void* d_out, int out_size, void* d_ws, size_t ws_size,
                              hipStream_t stream) {
    const float* feats  = (const float*)d_in[0];
    const float* trans  = (const float*)d_in[1];
    const float* tstart = (const float*)d_in[2];
    const float* tstop  = (const float*)d_in[3];
    const int*   tags   = (const int*)d_in[4];
    float* out = (float*)d_out;

    hipLaunchKernelGGL(crf_init, dim3(2), dim3(1024), 0, stream, feats, tstart);
    hipLaunchKernelGGL(crf_gold, dim3(1), dim3(1024), 0, stream,
                       feats, trans, tstart, tstop, tags);
    hipLaunchKernelGGL(crf_main, dim3(NBLK), dim3(NTHR), 0, stream,
                       feats, trans, tstop, out);
}